// Round 16
// baseline (656.328 us; speedup 1.0000x reference)
//
#include <hip/hip_runtime.h>

#define LOG2E 1.4426950408889634f
#define LN2   0.6931471805599453f

typedef float f32x2 __attribute__((ext_vector_type(2)));

// r11 verified base (98 us, absmax 0): linear-domain fwd/bwd split,
//   alpha_t = D_t M alpha_{t-1},  beta_{t-1} = M^T (d_t beta_t),
// LDS uniform-address ds_read_b128 broadcast, v_pk_fma_f32 matvec,
// immediate integer-exponent rescale every 2 steps, join Z = beta_m^T alpha_m.
//
// Round-16: BOTH chains in ONE wave. Evidence: r11 step = 459 cyc ~= 175
// VALU issue + ~280 irreducible latency (LDS write->read RAW + tail); all
// within-chain attacks on the latency term failed (r14 read-halving null,
// r15 manual pipeline regressed — compiler's schedule is already optimal).
// Independent work in the same wave is the only structure that fills a RAW
// stall. r12's version of this died on the ~132-VGPR allocator cliff
// (2x64 f32 M regs); fix = store both M fragments as packed bf16
// (32 u32/chain, 64 total), unpacked per use with 2 bit-ops per pair
// (exact bf16->f32). M=exp(trans) in bf16: per-step log error ~2^-9,
// absmax expected <=~1 vs threshold 106. Single wave also deletes the
// join barrier. No cross-wave sync anywhere (r1/r9/r12 lesson).
__device__ __forceinline__ unsigned bf16rne(float f) {
  unsigned u = __float_as_uint(f);
  u += 0x7fffu + ((u >> 16) & 1u);  // round-to-nearest-even on bit 16
  return u >> 16;
}
__device__ __forceinline__ f32x2 unpk(unsigned w) {
  f32x2 r;
  r.x = __uint_as_float(w << 16);          // low bf16 -> f32 (exact)
  r.y = __uint_as_float(w & 0xffff0000u);  // high bf16 -> f32 (exact)
  return r;
}

// One folded step of a chain: 16 uniform ds_read_b128 broadcasts of the
// 64-float state, 32 bf16 unpacks, 16 pk_fma, packed tree, rescale, write.
#define STEPC(PB, MB, B2, D, RESC) do {                                       \
    const float4* pb4_ = (const float4*)(PB);                                 \
    f32x2 a0_ = {0.f, 0.f}, a1_ = {0.f, 0.f}, a2_ = {0.f, 0.f},               \
          a3_ = {0.f, 0.f};                                                   \
    float p0_ = 0.f;                                                          \
    _Pragma("unroll")                                                         \
    for (int g = 0; g < 16; ++g) {                                            \
      float4 q_ = pb4_[g]; /* uniform addr -> broadcast, conflict-free */     \
      if (g == 0) p0_ = q_.x;                                                 \
      f32x2 qlo_ = {q_.x, q_.y}, qhi_ = {q_.z, q_.w};                         \
      f32x2 m0_ = unpk((MB)[2 * g + 0]), m1_ = unpk((MB)[2 * g + 1]);         \
      if ((g & 1) == 0) {                                                     \
        a0_ = __builtin_elementwise_fma(m0_, qlo_, a0_);                      \
        a1_ = __builtin_elementwise_fma(m1_, qhi_, a1_);                      \
      } else {                                                                \
        a2_ = __builtin_elementwise_fma(m0_, qlo_, a2_);                      \
        a3_ = __builtin_elementwise_fma(m1_, qhi_, a3_);                      \
      }                                                                       \
    }                                                                         \
    float mult_ = (D);                                                        \
    if (RESC) { /* anchor = replicated p[0] of the consumed state */          \
      int e_ = (int)((__float_as_uint(p0_) >> 23) & 0xffu);                   \
      (B2) += e_ - 127;                                                       \
      mult_ *= __uint_as_float((unsigned)(254 - e_) << 23); /* 2^(127-e) */   \
    }                                                                         \
    f32x2 s01_ = a0_ + a1_, s23_ = a2_ + a3_; /* v_pk_add_f32 */              \
    f32x2 s2_ = s01_ + s23_;                                                  \
    (PB)[lane] = (s2_.x + s2_.y) * mult_; /* 2-way bank alias = free */       \
  } while (0)

__global__ __launch_bounds__(64)
__attribute__((amdgpu_waves_per_eu(1, 1)))
void crf_fwd_33852932227637(
    const float* __restrict__ h,
    const float* __restrict__ trans,
    const int* __restrict__ lengths,
    float* __restrict__ out,
    int T) {
  constexpr int N = 64;
  const int b = blockIdx.x;
  const int lane = threadIdx.x;

  const float* hb = h + (size_t)b * T * N;
  const int len = lengths[b];
  const int m = (len - 1) >> 1;   // join point
  const int nsF = m;              // fwd folded steps (t = 1..m)
  const int nsB = len - 1 - m;    // bwd matvec count (t = len-1..m+1)
  const int nsBf = nsB - 1;       // bwd folded steps (final one raw)

  // M fragments in packed bf16: MbF = row `lane` of M = exp(trans);
  // MbB = column `lane` (row of M^T). 32 u32 regs each.
  unsigned MbF[32], MbB[32];
  {
    const float4* trow = (const float4*)(trans + lane * N);
#pragma unroll
    for (int q = 0; q < 16; ++q) {
      float4 tq = trow[q];
      unsigned x = bf16rne(__builtin_amdgcn_exp2f(tq.x * LOG2E));
      unsigned y = bf16rne(__builtin_amdgcn_exp2f(tq.y * LOG2E));
      unsigned z = bf16rne(__builtin_amdgcn_exp2f(tq.z * LOG2E));
      unsigned w = bf16rne(__builtin_amdgcn_exp2f(tq.w * LOG2E));
      MbF[2 * q + 0] = x | (y << 16);
      MbF[2 * q + 1] = z | (w << 16);
    }
#pragma unroll
    for (int q = 0; q < 32; ++q) {
      unsigned lo =
          bf16rne(__builtin_amdgcn_exp2f(trans[(2 * q + 0) * N + lane] * LOG2E));
      unsigned hi =
          bf16rne(__builtin_amdgcn_exp2f(trans[(2 * q + 1) * N + lane] * LOG2E));
      MbB[q] = lo | (hi << 16);
    }
  }
  // Pin into arch VGPRs (r2/r9/r12 tripwire: VGPR_Count in counters).
#pragma unroll
  for (int q = 0; q < 8; ++q) {
    asm volatile("" : "+v"(MbF[4 * q + 0]), "+v"(MbF[4 * q + 1]),
                      "+v"(MbF[4 * q + 2]), "+v"(MbF[4 * q + 3]));
    asm volatile("" : "+v"(MbB[4 * q + 0]), "+v"(MbB[4 * q + 1]),
                      "+v"(MbB[4 * q + 2]), "+v"(MbB[4 * q + 3]));
  }

  // State buffers; single wave owns both -> in-order DS, zero barriers.
  // Init: alpha_0[i] = exp(h[0,i]+trans[i,START]); beta side = u_END[i] =
  // exp(trans[END,i]) with d_{len-1} folded when a matvec exists. START=N-2.
  __shared__ __align__(16) float pbuf[2][N];
  pbuf[0][lane] =
      __builtin_amdgcn_exp2f((hb[lane] + trans[lane * N + (N - 2)]) * LOG2E);
  {
    float v = __builtin_amdgcn_exp2f(trans[(N - 1) * N + lane] * LOG2E);
    if (nsB >= 1)
      v *= __builtin_amdgcn_exp2f(hb[(size_t)(len - 1) * N + lane] * LOG2E);
    pbuf[1][lane] = v;
  }
  int b2F = 0, b2B = 0;

  // Emissions for folded step s: fwd consumes d_s; bwd consumes d_{len-1-s}.
  // Clamped addresses (value unused when clamped; address stays in range).
  auto emitF = [&](int s_) -> float {
    int smax = nsF < 1 ? 1 : nsF;
    int sc2 = s_ < smax ? s_ : smax;
    if (sc2 < 1) sc2 = 1;
    return __builtin_amdgcn_exp2f(hb[(size_t)sc2 * N + lane] * LOG2E);
  };
  auto emitB = [&](int s_) -> float {
    int smax = nsBf < 1 ? 1 : nsBf;
    int sc2 = s_ < smax ? s_ : smax;
    if (sc2 < 1) sc2 = 1;
    int t = len - 1 - sc2;
    if (t < 0) t = 0;
    return __builtin_amdgcn_exp2f(hb[(size_t)t * N + lane] * LOG2E);
  };

  // Interleaved main loop. len-1 even: nsBf = nsF-1 -> sc = nsF-1, one fwd
  // leftover; len-1 odd: nsBf = nsF -> sc = nsF, none. (len=1: sc = -1.)
  const int sc = nsF < nsBf ? nsF : nsBf;
  float ebF[4], ebB[4];
#pragma unroll
  for (int u = 0; u < 4; ++u) {
    ebF[u] = emitF(1 + u);
    ebB[u] = emitB(1 + u);
  }

  int s = 1;
  for (; s + 4 <= sc + 1; s += 4) {
#pragma unroll
    for (int u = 0; u < 4; ++u) {
      STEPC(pbuf[0], MbF, b2F, ebF[u], (u & 1) == 1);
      STEPC(pbuf[1], MbB, b2B, ebB[u], (u & 1) == 1);
      ebF[u] = emitF(s + u + 4);
      ebB[u] = emitB(s + u + 4);
    }
  }
  for (; s <= sc; ++s) {  // tail: slot (s-1)&3 holds d for step s
    STEPC(pbuf[0], MbF, b2F, ebF[(s - 1) & 3], true);
    STEPC(pbuf[1], MbB, b2B, ebB[(s - 1) & 3], true);
  }
  // Fwd leftover (<=1 step, when len-1 even and nsF >= 1).
  for (int s2 = sc + 1; s2 <= nsF; ++s2)
    STEPC(pbuf[0], MbF, b2F, ebF[(s2 - 1) & 3], true);
  // Final raw bwd step (beta_m excludes d_m).
  if (nsB >= 1) STEPC(pbuf[1], MbB, b2B, 1.0f, true);

  // Join in-wave: Z * 2^-(b2F+b2B) = sum_i alpha_m[i] * beta_m[i]; anchors
  // keep both factors ~2^0, so the dot neither over- nor underflows.
  float z = pbuf[0][lane] * pbuf[1][lane];
#pragma unroll
  for (int off = 32; off >= 1; off >>= 1)
    z += __shfl_xor(z, off, 64);
  if (lane == 0)
    out[b] = LN2 * ((float)(b2F + b2B) + __builtin_amdgcn_logf(z));
}

extern "C" void kernel_launch(void* const* d_in, const int* in_sizes, int n_in,
                              void* d_out, int out_size, void* d_ws, size_t ws_size,
                              hipStream_t stream) {
  const float* h = (const float*)d_in[0];
  const float* trans = (const float*)d_in[1];
  const int* lengths = (const int*)d_in[2];
  float* out = (float*)d_out;
  const int B = in_sizes[2];
  const int N = 64;
  const int T = in_sizes[0] / (B * N);
  crf_fwd_33852932227637<<<B, N, 0, stream>>>(h, trans, lengths, out, T);
}